// Round 8
// baseline (329.665 us; speedup 1.0000x reference)
//
#include <hip/hip_runtime.h>
#include <math.h>

typedef unsigned short u16;
typedef __attribute__((ext_vector_type(8))) short bf16x8;
typedef __attribute__((ext_vector_type(4))) float f32x4;
typedef __attribute__((ext_vector_type(16))) float f32x16;

// workspace layout (bf16 elements)
constexpr int OFF_W1 = 0;          // [3][128][128]  (l, h, c)
constexpr int OFF_W2 = 49152;      // [3][128][128]  (l, c, h)
constexpr int OFF_GW = 98304;      // [256][128]     (o, h)
constexpr int OFF_TG = 131072;     // [64][16]  rows>=42 / cols>=9 zero
constexpr int OFF_FG = 132096;     // [32][48]  rows>=9  / cols>=42 zero
constexpr int WS_ELEMS = 133632;   // bytes needed in d_ws = 267264

// f32 -> bf16 RNE via native compiler cast (gfx950: lowers to v_cvt_pk_bf16_f32).
__device__ __forceinline__ u16 f2bf(float f) {
    union { __bf16 b; u16 u; } cv;
    cv.b = (__bf16)f;
    return cv.u;
}
// packed pair: lo = cvt(a), hi = cvt(b)
__device__ __forceinline__ unsigned f2bf2(float a, float b) {
    return (unsigned)f2bf(a) | ((unsigned)f2bf(b) << 16);
}

__global__ void prep_kernel(const float* __restrict__ w1, const float* __restrict__ gw,
                            const float* __restrict__ w2, const float* __restrict__ tg,
                            const float* __restrict__ fg, u16* __restrict__ wsb) {
    const int idx = blockIdx.x * blockDim.x + threadIdx.x;
    const int str = gridDim.x * blockDim.x;
    for (int i = idx; i < 49152; i += str) wsb[OFF_W1 + i] = f2bf(w1[i]);
    for (int i = idx; i < 49152; i += str) wsb[OFF_W2 + i] = f2bf(w2[i]);
    for (int i = idx; i < 32768; i += str) wsb[OFF_GW + i] = f2bf(gw[i]);
    for (int i = idx; i < 1024; i += str) {
        int a = i >> 4, k = i & 15;
        wsb[OFF_TG + i] = (a < 42 && k < 9) ? f2bf(tg[a * 9 + k]) : (u16)0;
    }
    for (int i = idx; i < 1536; i += str) {
        int m = i / 48, k = i - m * 48;
        wsb[OFF_FG + i] = (m < 9 && k < 42) ? f2bf(fg[m * 42 + k]) : (u16)0;
    }
}

// 2 nodes per 256-thread WG.  LDS ~40 KB -> target 4 WG/CU (16 waves/CU).
// No sh_g2T: swiglu output -> from_grid B-fragments assembled IN REGISTERS via
// one shfl_xor(.,16) per packed word (lanes {l, l^16} hold each other's halves).
// batched-row layout (48 rows, degree-pure 16-row tiles):
//   l0: row = node (0..1); l1: row = 16 + node*3 + mm; l2: row = 32 + node*5 + mm
__global__ __launch_bounds__(256, 2) void eqffn_mfma(
    const float* __restrict__ x, const float* __restrict__ nw,
    const float* __restrict__ b1f, const float* __restrict__ gbf,
    const float* __restrict__ b2f, const u16* __restrict__ wsb,
    float* __restrict__ out, int N)
{
    __shared__ __align__(16) u16 sh_a1[48 * 136];      // A1 (packed acts), later h2b 13056 B
    __shared__ __align__(16) u16 sh_h1T[2 * 128 * 20]; // [nd][h][m-pad20]; cols 9..19 zero 10240 B
    __shared__ __align__(16) u16 sh_g[48 * 136];       // current-node grid acts [a][h] 13056 B
    __shared__ float sh_nw[384];
    __shared__ float sh_b1[128];
    __shared__ float sh_b2[128];
    __shared__ float sh_gb[256];
    __shared__ float sh_red[4];       // RMS partial sums (wave pairs)

    const int tid  = threadIdx.x;
    const int w    = tid >> 6;       // wave id
    const int lane = tid & 63;
    const int q    = lane >> 4;      // 16x16 quad (0..3)
    const int r    = lane & 15;
    const int r32  = lane & 31;      // 32x32 row/col
    const int half = lane >> 5;
    const int pc   = q & 1;          // my swiglu column's p index (o = (2w+pc)*16 + r)
    const int n0   = blockIdx.x * 2;

    // ---- small hoisted weight fragments (L2-resident, 5 frags = 20 VGPR) ----
    const bf16x8 tgA0 = *(const bf16x8*)&wsb[OFF_TG + r32 * 16 + half * 8];
    const bf16x8 tgA1 = *(const bf16x8*)&wsb[OFF_TG + (32 + r32) * 16 + half * 8];
    bf16x8 fgA[3];
    #pragma unroll
    for (int k = 0; k < 3; ++k)
        fgA[k] = *(const bf16x8*)&wsb[OFF_FG + r32 * 48 + k * 16 + half * 8];

    // ---- init: stage small vectors, zero h1T pad region ----
    for (int i = tid; i < 384; i += 256) sh_nw[i] = nw[i];
    if (tid < 128) { sh_b1[tid] = b1f[tid]; sh_b2[tid] = b2f[tid]; }
    sh_gb[tid] = gbf[tid];
    {
        unsigned long long* z1 = (unsigned long long*)sh_h1T;
        for (int i = tid; i < 1280; i += 256) z1[i] = 0ull;
    }

    // ---- phase A: wave pair (2*nd, 2*nd+1) loads node n0+nd; half ph each ----
    const int nd0 = w >> 1;          // node this wave helps load (0..1)
    const int ph  = w & 1;           // which half of the 1152 floats
    const int myn = n0 + nd0;
    float4 xv[3];
    float ss = 0.f;
    if (myn < N) {
        const float4* xr = (const float4*)(x + (size_t)myn * 1152 + ph * 576);
        for (int i = lane, c2 = 0; i < 144; i += 64, ++c2) {
            float4 v = xr[i]; xv[c2] = v;
            ss += v.x * v.x + v.y * v.y + v.z * v.z + v.w * v.w;
        }
    }
    #pragma unroll
    for (int off = 32; off; off >>= 1) ss += __shfl_xor(ss, off);
    if (lane == 0) sh_red[w] = ss;
    __syncthreads();   // init + partial sums visible

    const float sstot = sh_red[2 * nd0] + sh_red[2 * nd0 + 1];
    const float inv = 1.0f / sqrtf(sstot * (1.0f / 1152.0f) + 1e-6f);
    if (myn < N) {
        for (int i = lane, c2 = 0; i < 144; i += 64, ++c2) {
            float4 v = xv[c2];
            #pragma unroll
            for (int e = 0; e < 4; ++e) {
                const int f = ph * 576 + i * 4 + e;
                const float val = ((const float*)&v)[e] * inv;
                int row, c, l;
                if (f < 128)      { l = 0; c = f;            row = nd0; }
                else if (f < 512) { int t = f - 128; l = 1; c = t / 3; row = 16 + nd0 * 3 + (t - c * 3); }
                else              { int t = f - 512; l = 2; c = t / 5; row = 32 + nd0 * 5 + (t - c * 5); }
                sh_a1[row * 136 + c] = f2bf(val * sh_nw[l * 128 + c]);
            }
        }
    }
    __syncthreads();   // A1 ready

    // ---- GEMM1 (3 degree-pure tiles, 16x16x32): h1[row][h] = sum_c A1[row][c] w1[l][h][c]
    {
        f32x4 acc1[3][2];
        #pragma unroll
        for (int a = 0; a < 3; ++a)
            #pragma unroll
            for (int b = 0; b < 2; ++b)
                #pragma unroll
                for (int e = 0; e < 4; ++e) acc1[a][b][e] = 0.f;
        #pragma unroll
        for (int mt = 0; mt < 3; ++mt) {           // l == mt
            #pragma unroll
            for (int k = 0; k < 4; ++k) {
                bf16x8 af = *(const bf16x8*)&sh_a1[(mt * 16 + r) * 136 + k * 32 + q * 8];
                #pragma unroll
                for (int nt = 0; nt < 2; ++nt) {
                    const int h = (2 * w + nt) * 16 + r;
                    bf16x8 bf = *(const bf16x8*)&wsb[OFF_W1 + (mt * 128 + h) * 128 + k * 32 + q * 8];
                    acc1[mt][nt] = __builtin_amdgcn_mfma_f32_16x16x32_bf16(af, bf, acc1[mt][nt], 0, 0, 0);
                }
            }
        }
        // epilogue: +b1 on l0, write both nodes' h1T slices (wave-local h columns)
        #pragma unroll
        for (int mt = 0; mt < 3; ++mt) {
            #pragma unroll
            for (int nt = 0; nt < 2; ++nt) {
                const int h = (2 * w + nt) * 16 + r;
                #pragma unroll
                for (int rg = 0; rg < 4; ++rg) {
                    const int rr = q * 4 + rg;
                    const float v = acc1[mt][nt][rg];
                    if (mt == 0) {
                        if (rr < 2) sh_h1T[rr * 2560 + h * 20 + 0] = f2bf(v + sh_b1[h]);
                    } else if (mt == 1) {
                        if (rr < 6) { int nd = rr / 3, mm = rr - nd * 3; sh_h1T[nd * 2560 + h * 20 + 1 + mm] = f2bf(v); }
                    } else {
                        if (rr < 10) { int nd = rr / 5, mm = rr - nd * 5; sh_h1T[nd * 2560 + h * 20 + 4 + mm] = f2bf(v); }
                    }
                }
            }
        }
    }
    // No barrier: h1T rows h in [32w,32w+32) are wave-local (written+read by wave w).

    // ---- per-node grid pipeline (2 iterations) ----
    for (int nn = 0; nn < 2; ++nn) {
        // to_grid (32x32x16): g[a][h] = sum_m tg[a][m] h1[nn][m][h]; wave w -> h block w*32
        {
            bf16x8 bfn = *(const bf16x8*)&sh_h1T[nn * 2560 + (w * 32 + r32) * 20 + half * 8];
            f32x16 ac0, ac1;
            #pragma unroll
            for (int e = 0; e < 16; ++e) { ac0[e] = 0.f; ac1[e] = 0.f; }
            ac0 = __builtin_amdgcn_mfma_f32_32x32x16_bf16(tgA0, bfn, ac0, 0, 0, 0);
            ac1 = __builtin_amdgcn_mfma_f32_32x32x16_bf16(tgA1, bfn, ac1, 0, 0, 0);
            const int h = w * 32 + r32;
            #pragma unroll
            for (int rg = 0; rg < 16; ++rg) {
                const int ar = (rg & 3) + 8 * (rg >> 2) + 4 * half;
                sh_g[ar * 136 + h] = f2bf(ac0[rg]);
                const int ar1 = 32 + ar;
                if (ar1 < 48) sh_g[ar1 * 136 + h] = f2bf(ac1[rg]);
            }
        }
        __syncthreads();   // g ready (nn==0: also orders GEMM1 a1-reads vs h2b writes)

        // SwiGLU swapped (A=g-frag, B=gw-frag): z[a][o] = sum_h g[a][h] gw[o][h]
        f32x4 sL[2][3], sH[2][3];   // [p][nt]
        #pragma unroll
        for (int p = 0; p < 2; ++p)
            #pragma unroll
            for (int nt = 0; nt < 3; ++nt)
                #pragma unroll
                for (int e = 0; e < 4; ++e) { sL[p][nt][e] = 0.f; sH[p][nt][e] = 0.f; }
        #pragma unroll
        for (int k = 0; k < 4; ++k) {
            bf16x8 bk[3];
            #pragma unroll
            for (int nt = 0; nt < 3; ++nt)
                bk[nt] = *(const bf16x8*)&sh_g[(nt * 16 + r) * 136 + k * 32 + q * 8];
            #pragma unroll
            for (int p = 0; p < 2; ++p) {
                const int oL = (2 * w + p) * 16 + r;
                bf16x8 fL = *(const bf16x8*)&wsb[OFF_GW + oL * 128 + k * 32 + q * 8];
                bf16x8 fH = *(const bf16x8*)&wsb[OFF_GW + (oL + 128) * 128 + k * 32 + q * 8];
                #pragma unroll
                for (int nt = 0; nt < 3; ++nt) {
                    sL[p][nt] = __builtin_amdgcn_mfma_f32_16x16x32_bf16(bk[nt], fL, sL[p][nt], 0, 0, 0);
                    sH[p][nt] = __builtin_amdgcn_mfma_f32_16x16x32_bf16(bk[nt], fH, sH[p][nt], 0, 0, 0);
                }
            }
        }
        if (nn == 0) __syncthreads();  // all g reads complete -> next iter may overwrite sh_g

        // silu -> gv in registers (a = nt*16 + q*4 + rg ; my two cols o=(2w+p)*16+r)
        float gv[2][3][4];
        #pragma unroll
        for (int p = 0; p < 2; ++p) {
            const int o  = (2 * w + p) * 16 + r;
            const float bL = sh_gb[o];
            const float bH = sh_gb[128 + o];
            #pragma unroll
            for (int nt = 0; nt < 3; ++nt) {
                #pragma unroll
                for (int rg = 0; rg < 4; ++rg) {
                    const float zl = sL[p][nt][rg] + bL;
                    const float zh = sH[p][nt][rg] + bH;
                    float g = zl * (1.0f / (1.0f + __expf(-zl))) * zh;
                    if (nt == 2 && (q * 4 + rg >= 10)) g = 0.f;   // a >= 42 pad
                    gv[p][nt][rg] = g;
                }
            }
        }

        // assemble from_grid B-fragments in registers:
        // lane l column h = w*32 + (l&31); needs a = kt*16 + half*8 + e.
        // my q holds e in [4*pc, 4*pc+4); partner (l^16) holds the other 4.
        bf16x8 bB[3];
        #pragma unroll
        for (int nt = 0; nt < 3; ++nt) {
            const unsigned pkA0 = f2bf2(gv[0][nt][0], gv[0][nt][1]);
            const unsigned pkA1 = f2bf2(gv[0][nt][2], gv[0][nt][3]);
            const unsigned pkB0 = f2bf2(gv[1][nt][0], gv[1][nt][1]);
            const unsigned pkB1 = f2bf2(gv[1][nt][2], gv[1][nt][3]);
            const unsigned keep0 = pc ? pkB0 : pkA0;   // my column, my e-half
            const unsigned keep1 = pc ? pkB1 : pkA1;
            const unsigned send0 = pc ? pkA0 : pkB0;   // partner's column, my e-half
            const unsigned send1 = pc ? pkA1 : pkB1;
            const unsigned recv0 = (unsigned)__shfl_xor((int)send0, 16, 64);
            const unsigned recv1 = (unsigned)__shfl_xor((int)send1, 16, 64);
            union { unsigned u[4]; bf16x8 v; } bw;
            bw.u[0] = pc ? recv0 : keep0;   // e {0,1}
            bw.u[1] = pc ? recv1 : keep1;   // e {2,3}
            bw.u[2] = pc ? keep0 : recv0;   // e {4,5}
            bw.u[3] = pc ? keep1 : recv1;   // e {6,7}
            bB[nt] = bw.v;
        }

        // from_grid (32x32x16, K=48, pure-register B): h2[m][h] = sum_a fg[m][a] g2[a][h]
        {
            f32x16 ac;
            #pragma unroll
            for (int e = 0; e < 16; ++e) ac[e] = 0.f;
            #pragma unroll
            for (int kt = 0; kt < 3; ++kt)
                ac = __builtin_amdgcn_mfma_f32_32x32x16_bf16(fgA[kt], bB[kt], ac, 0, 0, 0);
            const int h = w * 32 + r32;
            #pragma unroll
            for (int rg = 0; rg < 16; ++rg) {
                const int m = (rg & 3) + 8 * (rg >> 2) + 4 * half;
                if (m < 9) {
                    const int row = (m == 0) ? nn : ((m < 4) ? (16 + nn * 3 + (m - 1)) : (32 + nn * 5 + (m - 4)));
                    sh_a1[row * 136 + h] = f2bf(ac[rg]);
                }
            }
        }
    }
    __syncthreads();

    // ---- GEMM2 (3 degree-pure tiles, 16x16x32) + bias + unpack scatter store ----
    {
        f32x4 acc[3][2];
        #pragma unroll
        for (int a = 0; a < 3; ++a)
            #pragma unroll
            for (int b = 0; b < 2; ++b)
                #pragma unroll
                for (int e = 0; e < 4; ++e) acc[a][b][e] = 0.f;
        #pragma unroll
        for (int mt = 0; mt < 3; ++mt) {           // l == mt
            #pragma unroll
            for (int k = 0; k < 4; ++k) {
                bf16x8 af = *(const bf16x8*)&sh_a1[(mt * 16 + r) * 136 + k * 32 + q * 8];
                #pragma unroll
                for (int nt = 0; nt < 2; ++nt) {
                    const int c = (2 * w + nt) * 16 + r;
                    bf16x8 bf = *(const bf16x8*)&wsb[OFF_W2 + (mt * 128 + c) * 128 + k * 32 + q * 8];
                    acc[mt][nt] = __builtin_amdgcn_mfma_f32_16x16x32_bf16(af, bf, acc[mt][nt], 0, 0, 0);
                }
            }
        }
        #pragma unroll
        for (int mt = 0; mt < 3; ++mt) {
            #pragma unroll
            for (int nt = 0; nt < 2; ++nt) {
                const int c = (2 * w + nt) * 16 + r;
                #pragma unroll
                for (int rg = 0; rg < 4; ++rg) {
                    const int rr = q * 4 + rg;
                    const float v = acc[mt][nt][rg];
                    if (mt == 0) {
                        if (rr < 2) { int gn = n0 + rr; if (gn < N) out[(size_t)gn * 1152 + c] = v + sh_b2[c]; }
                    } else if (mt == 1) {
                        if (rr < 6) { int nd = rr / 3, mm = rr - nd * 3; int gn = n0 + nd;
                                      if (gn < N) out[(size_t)gn * 1152 + 128 + c * 3 + mm] = v; }
                    } else {
                        if (rr < 10) { int nd = rr / 5, mm = rr - nd * 5; int gn = n0 + nd;
                                       if (gn < N) out[(size_t)gn * 1152 + 512 + c * 5 + mm] = v; }
                    }
                }
            }
        }
    }
}

extern "C" void kernel_launch(void* const* d_in, const int* in_sizes, int n_in,
                              void* d_out, int out_size, void* d_ws, size_t ws_size,
                              hipStream_t stream)
{
    const float* x  = (const float*)d_in[0];
    const float* nw = (const float*)d_in[1];
    const float* w1 = (const float*)d_in[2];
    const float* b1 = (const float*)d_in[3];
    const float* gw = (const float*)d_in[4];
    const float* gb = (const float*)d_in[5];
    const float* w2 = (const float*)d_in[6];
    const float* b2 = (const float*)d_in[7];
    const float* tg = (const float*)d_in[8];
    const float* fg = (const float*)d_in[9];
    float* out = (float*)d_out;
    u16* wsb = (u16*)d_ws;

    const int N = in_sizes[0] / 1152;
    prep_kernel<<<64, 256, 0, stream>>>(w1, gw, w2, tg, fg, wsb);
    eqffn_mfma<<<(N + 1) / 2, 256, 0, stream>>>(x, nw, b1, gb, b2, wsb, out, N);
}